// Round 2
// baseline (248.699 us; speedup 1.0000x reference)
//
#include <hip/hip_runtime.h>
#include <math.h>

#define PI_D 3.14159265358979323846
#define PI_F 3.14159265358979323846f

// ---------------- scatter: remap + gaussian gridding (w channel only, fp32) ----------------
__global__ void k_scatter(const float* __restrict__ inp,
                          const float* __restrict__ p_scale,
                          const float* __restrict__ p_sigma,
                          const float* __restrict__ p_A,
                          const float* __restrict__ p_ic,
                          float* __restrict__ ft) {
  int i = blockIdx.x * 256 + threadIdx.x;           // 0 .. 262143
  float scale = p_scale[0];
  float sigma = p_sigma[0];
  float A     = p_A[0];
  float icomp = p_ic[0];
  int b = i >> 15;
  float x = inp[i*3+0];
  float y = inp[i*3+1];
  float z = inp[i*3+2];
  float r = sqrtf(x*x + y*y + z*z);
  r = fmaxf(r, 0.1f);
  float ctv = fminf(fmaxf(z / r, -1.0f), 1.0f);
  float theta = acosf(ctv);
  float phi = atan2f(y, x) + PI_F;
  float ct = theta * (32.0f / PI_F);
  float cp = phi * (32.0f / (2.0f * PI_F));
  float cr = r / scale * 8.0f;
  int it = (int)floorf(ct); it = min(max(it, 0), 31);
  int ip = (int)floorf(cp); ip = min(max(ip, 0), 31);
  int ir = (int)floorf(cr); ir = min(max(ir, 0), 7);
  float dt = ct - ((float)it + icomp);
  float dp = cp - ((float)ip + icomp);
  float dr = cr - ((float)ir + icomp);
  float d2 = dt*dt + dp*dp + dr*dr;
  float w = A * expf(-d2 / (2.0f * sigma * sigma));
  // ft layout: (b, ir, it, ip)  == transpose(grid[...,0],(0,3,1,2))
  atomicAdd(&ft[((b*8 + ir)*32 + it)*32 + ip], w);
}

// ---------------- quadrature weights (once, fp64, bw=16) ----------------
__global__ void k_wq(float* __restrict__ wq) {
  int t = threadIdx.x;             // 32
  double jj = 2.0*(double)t + 1.0;
  double theta = PI_D * jj / 64.0;
  double s = 0.0;
  for (int k = 0; k < 16; ++k)
    s += sin(jj * (double)(2*k+1) * PI_D / 64.0) / (double)(2*k+1);
  wq[t] = (float)((2.0/16.0) * sin(theta) * s);
}

// ---------------- conv1: (8,8,32,32) -> (8,32,32,32), 3x3 SAME + relu ----------------
__global__ void k_conv1(const float* __restrict__ ft, const float* __restrict__ W,
                        const float* __restrict__ bias, float* __restrict__ h1) {
  int blk = blockIdx.x;            // 256 = b(8) * oc(32)
  int b = blk >> 5, oc = blk & 31;
  __shared__ float Ws[72];
  int t = threadIdx.x;             // 1024
  if (t < 72) Ws[t] = W[oc*72 + t];
  __syncthreads();
  int x = t >> 5, y = t & 31;
  float acc = bias[oc];
  const float* fb = ft + b*8192;
  for (int ic = 0; ic < 8; ++ic) {
    const float* fc = fb + ic*1024;
    const float* wr = Ws + ic*9;
#pragma unroll
    for (int dx = -1; dx <= 1; ++dx) {
      int xx = x + dx;
      bool okx = ((unsigned)xx < 32u);
#pragma unroll
      for (int dy = -1; dy <= 1; ++dy) {
        int yy = y + dy;
        float v = (okx && ((unsigned)yy < 32u)) ? fc[xx*32 + yy] : 0.f;
        acc = fmaf(v, wr[(dx+1)*3 + (dy+1)], acc);
      }
    }
  }
  h1[(b*32 + oc)*1024 + t] = fmaxf(acc, 0.f);
}

// ---------------- conv2: (8,32,32,32) -> (8,64,32,32), 3x3 SAME + relu ----------------
__global__ __launch_bounds__(512) void k_conv2(const float* __restrict__ h1,
                        const float* __restrict__ W,
                        const float* __restrict__ bias, float* __restrict__ h2) {
  int blk = blockIdx.x;            // 256 = b(8) * q(32);  q = ocquad(16) * xhalf(2)
  int b = blk >> 5, q = blk & 31;
  int oc0 = (q >> 1) * 4, xh = q & 1;
  __shared__ float Ws[4*288];
  int t = threadIdx.x;             // 512
  for (int idx = t; idx < 4*288; idx += 512) Ws[idx] = W[oc0*288 + idx];
  __syncthreads();
  int x = xh*16 + (t >> 5), y = t & 31;
  float a0 = bias[oc0+0], a1 = bias[oc0+1], a2 = bias[oc0+2], a3 = bias[oc0+3];
  const float* hb = h1 + b*32*1024;
  for (int ic = 0; ic < 32; ++ic) {
    const float* hc = hb + ic*1024;
    const float* w0 = Ws + 0*288 + ic*9;
    const float* w1 = Ws + 1*288 + ic*9;
    const float* w2 = Ws + 2*288 + ic*9;
    const float* w3 = Ws + 3*288 + ic*9;
#pragma unroll
    for (int dx = -1; dx <= 1; ++dx) {
      int xx = x + dx;
      bool okx = ((unsigned)xx < 32u);
#pragma unroll
      for (int dy = -1; dy <= 1; ++dy) {
        int yy = y + dy;
        float v = (okx && ((unsigned)yy < 32u)) ? hc[xx*32 + yy] : 0.f;
        int k = (dx+1)*3 + (dy+1);
        a0 = fmaf(v, w0[k], a0);
        a1 = fmaf(v, w1[k], a1);
        a2 = fmaf(v, w2[k], a2);
        a3 = fmaf(v, w3[k], a3);
      }
    }
  }
  int p = x*32 + y;
  h2[(b*64 + oc0+0)*1024 + p] = fmaxf(a0, 0.f);
  h2[(b*64 + oc0+1)*1024 + p] = fmaxf(a1, 0.f);
  h2[(b*64 + oc0+2)*1024 + p] = fmaxf(a2, 0.f);
  h2[(b*64 + oc0+3)*1024 + p] = fmaxf(a3, 0.f);
}

// ---------------- reduce: ft_max[b,c] = (sum_g Wg[c,g]) * sum_{x,y} h2*wq[y] ----------------
__global__ void k_reduce(const float* __restrict__ h2, const float* __restrict__ Wg,
                         const float* __restrict__ wq, float* __restrict__ ftmax) {
  int blk = blockIdx.x;            // 512 = b(8)*c(64)
  int b = blk >> 6, c = blk & 63;
  __shared__ float wqs[32];
  __shared__ float red[256];
  int t = threadIdx.x;             // 256
  if (t < 32) wqs[t] = wq[t];
  __syncthreads();
  const float* hb = h2 + (b*64 + c)*1024;
  float acc = 0.f;
  for (int i = t; i < 1024; i += 256) acc = fmaf(hb[i], wqs[i & 31], acc);
  red[t] = acc;
  __syncthreads();
  for (int s2 = 128; s2 > 0; s2 >>= 1) {
    if (t < s2) red[t] += red[t + s2];
    __syncthreads();
  }
  if (t == 0) {
    float sg = 0.f;
    for (int g = 0; g < 32; ++g) sg += Wg[c*32 + g];
    ftmax[b*64 + c] = sg * red[0];
  }
}

// ---------------- head: h3 = relu(h2*Wg ⊗ Wc31 + K), out = h3*Wc32^T + b ----------------
// Tiles over y (pairs); per tile computes h3[y2][d][g] in LDS, then emits out
// with g-contiguous (128B/16-lane) coalesced stores.
__global__ __launch_bounds__(512) void k_head(
    const float* __restrict__ h2, const float* __restrict__ ftmax,
    const float* __restrict__ Wc31, const float* __restrict__ bc31,
    const float* __restrict__ Wc32, const float* __restrict__ bc32,
    const float* __restrict__ Wg, float* __restrict__ out,
    float* __restrict__ blockmax) {
  __shared__ float h2s[32*65];                    // [y][c] (+pad)
  __shared__ float Wgst[32*65];                   // [g][c] (+pad: bank = (g+c)%32)
  __shared__ __align__(16) float Ut[64*64];       // [c][d]  (float4 over d)
  __shared__ float W2s[64*32];                    // [d][e]
  __shared__ __align__(16) float h3s[2*64*32];    // [yy][d][g]
  __shared__ float Ks[64];
  __shared__ float b2s[32];
  __shared__ float vbuf[512];
  int blk = blockIdx.x;            // 256 = b(8)*x(32)
  int b = blk >> 5, x = blk & 31;
  int t = threadIdx.x;             // 512

  for (int idx = t; idx < 2048; idx += 512) {
    int y = idx & 31, c = idx >> 5;
    h2s[y*65 + c] = h2[(b*64 + c)*1024 + x*32 + y];
  }
  for (int idx = t; idx < 2048; idx += 512) {
    int c = idx & 63, g = idx >> 6;
    Wgst[g*65 + c] = Wg[c*32 + g];
  }
  for (int idx = t; idx < 4096; idx += 512) {
    int d = idx & 63, c = idx >> 6;
    Ut[idx] = Wc31[d*128 + c];
  }
  for (int idx = t; idx < 2048; idx += 512) {
    int e = idx & 31, d = idx >> 5;
    W2s[idx] = Wc32[e*64 + d];
  }
  if (t < 64) {
    float acc = bc31[t];
    for (int c = 0; c < 64; ++c)
      acc = fmaf(Wc31[t*128 + 64 + c], ftmax[b*64 + c], acc);
    Ks[t] = acc;
  }
  if (t < 32) b2s[t] = bc32[t];
  __syncthreads();

  // phase A mapping: g = t&31, dt = t>>5 (16), d4 = dt*4 -> acc[2y][4d]
  const int gA = t & 31, dt = t >> 5, d4 = dt * 4;
  // phase B mapping: g2 = (t&15)*2, e = t>>4 (32) -> acc[2y][2g]
  const int g2 = (t & 15) * 2, e = t >> 4;
  const float4* Ut4 = (const float4*)Ut;
  const float kx_ = Ks[d4], ky_ = Ks[d4+1], kz_ = Ks[d4+2], kw_ = Ks[d4+3];
  const float bb = b2s[e];
  float vmax = -3.4e38f;

  for (int yq = 0; yq < 16; ++yq) {
    int y0 = yq * 2;
    // ---- phase A: h3[y0..y0+1][d][g] ----
    {
      float4 acc0 = make_float4(kx_, ky_, kz_, kw_);
      float4 acc1 = acc0;
      const float* h2rA = h2s + y0*65;         // wave-uniform rows
      const float* h2rB = h2s + (y0+1)*65;
      const float* wgr  = Wgst + gA*65;
#pragma unroll 4
      for (int c = 0; c < 64; ++c) {
        float4 u = Ut4[c*16 + dt];
        float wg = wgr[c];
        float a0 = h2rA[c] * wg;
        float a1 = h2rB[c] * wg;
        acc0.x = fmaf(a0, u.x, acc0.x); acc0.y = fmaf(a0, u.y, acc0.y);
        acc0.z = fmaf(a0, u.z, acc0.z); acc0.w = fmaf(a0, u.w, acc0.w);
        acc1.x = fmaf(a1, u.x, acc1.x); acc1.y = fmaf(a1, u.y, acc1.y);
        acc1.z = fmaf(a1, u.z, acc1.z); acc1.w = fmaf(a1, u.w, acc1.w);
      }
      // relu + write [yy][d][g]; bank = g -> conflict-free
      h3s[(0*64 + d4+0)*32 + gA] = fmaxf(acc0.x, 0.f);
      h3s[(0*64 + d4+1)*32 + gA] = fmaxf(acc0.y, 0.f);
      h3s[(0*64 + d4+2)*32 + gA] = fmaxf(acc0.z, 0.f);
      h3s[(0*64 + d4+3)*32 + gA] = fmaxf(acc0.w, 0.f);
      h3s[(1*64 + d4+0)*32 + gA] = fmaxf(acc1.x, 0.f);
      h3s[(1*64 + d4+1)*32 + gA] = fmaxf(acc1.y, 0.f);
      h3s[(1*64 + d4+2)*32 + gA] = fmaxf(acc1.z, 0.f);
      h3s[(1*64 + d4+3)*32 + gA] = fmaxf(acc1.w, 0.f);
    }
    __syncthreads();
    // ---- phase B: out[e][y0..y0+1][g2..g2+1] ----
    {
      float b00 = bb, b01 = bb, b10 = bb, b11 = bb;   // [yy][gg]
#pragma unroll 4
      for (int d = 0; d < 64; ++d) {
        float w2 = W2s[d*32 + e];                      // 4 banks/wave, broadcast
        float2 h0 = *(const float2*)&h3s[(0*64 + d)*32 + g2];  // conflict-free
        float2 h1v = *(const float2*)&h3s[(1*64 + d)*32 + g2];
        b00 = fmaf(h0.x, w2, b00);
        b01 = fmaf(h0.y, w2, b01);
        b10 = fmaf(h1v.x, w2, b10);
        b11 = fmaf(h1v.y, w2, b11);
      }
      // out[(((b*32+e)*32+x)*32+y)*32+g] — lanes cover g-contiguous 128B lines
      size_t base = ((((size_t)b*32 + e)*32 + x)*32 + y0)*32;
      *(float2*)&out[base + g2]      = make_float2(b00, b01);
      *(float2*)&out[base + 32 + g2] = make_float2(b10, b11);
      vmax = fmaxf(vmax, fmaxf(fmaxf(b00, b01), fmaxf(b10, b11)));
    }
    __syncthreads();
  }
  vbuf[t] = vmax;
  __syncthreads();
  if (t < 32) {
    // threads with e == t are t*16 .. t*16+15
    float m = vbuf[t*16];
    for (int j = 1; j < 16; ++j) m = fmaxf(m, vbuf[t*16 + j]);
    blockmax[blk*32 + t] = m;
  }
}

// ---------------- finalize: ft_g[b,e] = max over x of blockmax ----------------
__global__ void k_final(const float* __restrict__ blockmax, float* __restrict__ ftg) {
  int t = threadIdx.x;             // 256 = b(8)*e(32)
  int b = t >> 5, e = t & 31;
  float m = -3.4e38f;
  for (int x = 0; x < 32; ++x) m = fmaxf(m, blockmax[(b*32 + x)*32 + e]);
  ftg[b*32 + e] = m;
}

extern "C" void kernel_launch(void* const* d_in, const int* in_sizes, int n_in,
                              void* d_out, int out_size, void* d_ws, size_t ws_size,
                              hipStream_t stream) {
  const float* inputs = (const float*)d_in[0];
  const float* scale  = (const float*)d_in[1];
  const float* sigma  = (const float*)d_in[2];
  const float* A      = (const float*)d_in[3];
  const float* icmp   = (const float*)d_in[4];
  // d_in[5]=res_pt(32), d_in[6]=res_r(8) — compile-time constants here
  const float* W1   = (const float*)d_in[7];
  const float* b1   = (const float*)d_in[8];
  const float* W2   = (const float*)d_in[9];
  const float* b2   = (const float*)d_in[10];
  const float* Wg   = (const float*)d_in[11];
  const float* Wc31 = (const float*)d_in[12];
  const float* bc31 = (const float*)d_in[13];
  const float* Wc32 = (const float*)d_in[14];
  const float* bc32 = (const float*)d_in[15];

  float* ws    = (float*)d_ws;
  float* ft    = ws;               // 65536
  float* h1    = ws + 65536;       // 262144
  float* h2    = ws + 327680;      // 524288
  float* ftmax = ws + 851968;      // 512
  float* bmax  = ws + 852480;      // 8192
  float* wq    = ws + 860672;      // 32
  float* out   = (float*)d_out;    // 8388608
  float* ftg   = out + 8388608;    // 256

  hipMemsetAsync(ft, 0, 65536*sizeof(float), stream);
  k_wq<<<1, 32, 0, stream>>>(wq);
  k_scatter<<<1024, 256, 0, stream>>>(inputs, scale, sigma, A, icmp, ft);
  k_conv1<<<256, 1024, 0, stream>>>(ft, W1, b1, h1);
  k_conv2<<<256, 512, 0, stream>>>(h1, W2, b2, h2);
  k_reduce<<<512, 256, 0, stream>>>(h2, Wg, wq, ftmax);
  k_head<<<256, 512, 0, stream>>>(h2, ftmax, Wc31, bc31, Wc32, bc32, Wg, out, bmax);
  k_final<<<1, 256, 0, stream>>>(bmax, ftg);
}

// Round 3
// 179.816 us; speedup vs baseline: 1.3831x; 1.3831x over previous
//
#include <hip/hip_runtime.h>
#include <math.h>

#define PI_D 3.14159265358979323846
#define PI_F 3.14159265358979323846f

typedef _Float16 half8 __attribute__((ext_vector_type(8)));
typedef _Float16 half2v __attribute__((ext_vector_type(2)));
typedef float floatx4 __attribute__((ext_vector_type(4)));
#define MFMA16(a,b,c) __builtin_amdgcn_mfma_f32_16x16x32_f16(a,b,c,0,0,0)

// ---------------- scatter: remap + gaussian gridding (w channel only, fp32) ----------------
__global__ void k_scatter(const float* __restrict__ inp,
                          const float* __restrict__ p_scale,
                          const float* __restrict__ p_sigma,
                          const float* __restrict__ p_A,
                          const float* __restrict__ p_ic,
                          float* __restrict__ ft) {
  int i = blockIdx.x * 256 + threadIdx.x;           // 0 .. 262143
  float scale = p_scale[0];
  float sigma = p_sigma[0];
  float A     = p_A[0];
  float icomp = p_ic[0];
  int b = i >> 15;
  float x = inp[i*3+0];
  float y = inp[i*3+1];
  float z = inp[i*3+2];
  float r = sqrtf(x*x + y*y + z*z);
  r = fmaxf(r, 0.1f);
  float ctv = fminf(fmaxf(z / r, -1.0f), 1.0f);
  float theta = acosf(ctv);
  float phi = atan2f(y, x) + PI_F;
  float ct = theta * (32.0f / PI_F);
  float cp = phi * (32.0f / (2.0f * PI_F));
  float cr = r / scale * 8.0f;
  int it = (int)floorf(ct); it = min(max(it, 0), 31);
  int ip = (int)floorf(cp); ip = min(max(ip, 0), 31);
  int ir = (int)floorf(cr); ir = min(max(ir, 0), 7);
  float dt = ct - ((float)it + icomp);
  float dp = cp - ((float)ip + icomp);
  float dr = cr - ((float)ir + icomp);
  float d2 = dt*dt + dp*dp + dr*dr;
  float w = A * expf(-d2 / (2.0f * sigma * sigma));
  atomicAdd(&ft[((b*8 + ir)*32 + it)*32 + ip], w);
}

// ---------------- quadrature weights (once, fp64, bw=16) ----------------
__global__ void k_wq(float* __restrict__ wq) {
  int t = threadIdx.x;             // 32
  double jj = 2.0*(double)t + 1.0;
  double theta = PI_D * jj / 64.0;
  double s = 0.0;
  for (int k = 0; k < 16; ++k)
    s += sin(jj * (double)(2*k+1) * PI_D / 64.0) / (double)(2*k+1);
  wq[t] = (float)((2.0/16.0) * sin(theta) * s);
}

// ---------------- prep: V[(g,d),c] = Wg[c,g]*Wc31[d,c], split f16, A-frag swizzled --------
// A-frag (16x16x32, M-side): lane holds A[m = mt*16 + (lane&15)][k = ks*32 + (lane>>4)*8 + jj]
// storage: flat = (((mt*2+ks)*64)+lane)*8 + jj
__global__ void k_prepV(const float* __restrict__ Wg, const float* __restrict__ Wc31,
                        _Float16* __restrict__ VswH, _Float16* __restrict__ VswL) {
  int flat = blockIdx.x * 256 + threadIdx.x;        // 0 .. 131071
  int jj = flat & 7;
  int l  = (flat >> 3) & 63;
  int rest = flat >> 9;                             // mt*2 + ks
  int ks = rest & 1, mt = rest >> 1;                // mt 0..127
  int c = ks*32 + (l >> 4)*8 + jj;                  // k = c
  int m = mt*16 + (l & 15);                         // m = g*64 + d
  int g = m >> 6, d = m & 63;
  float val = Wg[c*32 + g] * Wc31[d*128 + c];
  _Float16 hi = (_Float16)val;
  _Float16 lo = (_Float16)(val - (float)hi);
  VswH[flat] = hi;
  VswL[flat] = lo;
}

// ---------------- prep: W2 A-frags (GEMM2 M-side = e), split f16 ----------------
__global__ void k_prepW2(const float* __restrict__ Wc32,
                         _Float16* __restrict__ W2swH, _Float16* __restrict__ W2swL) {
  int flat = blockIdx.x * 256 + threadIdx.x;        // 0 .. 2047
  int jj = flat & 7;
  int l  = (flat >> 3) & 63;
  int rest = flat >> 9;                             // mt2*2 + ks, 0..3
  int ks = rest & 1, mt2 = rest >> 1;
  int e = mt2*16 + (l & 15);
  int d = ks*32 + (l >> 4)*8 + jj;
  float val = Wc32[e*64 + d];
  _Float16 hi = (_Float16)val;
  _Float16 lo = (_Float16)(val - (float)hi);
  W2swH[flat] = hi;
  W2swL[flat] = lo;
}

// ---------------- conv1: (8,8,32,32) -> (8,32,32,32), 3x3 SAME + relu ----------------
__global__ void k_conv1(const float* __restrict__ ft, const float* __restrict__ W,
                        const float* __restrict__ bias, float* __restrict__ h1) {
  int blk = blockIdx.x;            // 256 = b(8) * oc(32)
  int b = blk >> 5, oc = blk & 31;
  __shared__ float Ws[72];
  int t = threadIdx.x;             // 1024
  if (t < 72) Ws[t] = W[oc*72 + t];
  __syncthreads();
  int x = t >> 5, y = t & 31;
  float acc = bias[oc];
  const float* fb = ft + b*8192;
  for (int ic = 0; ic < 8; ++ic) {
    const float* fc = fb + ic*1024;
    const float* wr = Ws + ic*9;
#pragma unroll
    for (int dx = -1; dx <= 1; ++dx) {
      int xx = x + dx;
      bool okx = ((unsigned)xx < 32u);
#pragma unroll
      for (int dy = -1; dy <= 1; ++dy) {
        int yy = y + dy;
        float v = (okx && ((unsigned)yy < 32u)) ? fc[xx*32 + yy] : 0.f;
        acc = fmaf(v, wr[(dx+1)*3 + (dy+1)], acc);
      }
    }
  }
  h1[(b*32 + oc)*1024 + t] = fmaxf(acc, 0.f);
}

// ---------------- conv2: (8,32,32,32) -> (8,64,32,32), 3x3 SAME + relu ----------------
__global__ __launch_bounds__(512) void k_conv2(const float* __restrict__ h1,
                        const float* __restrict__ W,
                        const float* __restrict__ bias, float* __restrict__ h2) {
  int blk = blockIdx.x;            // 256 = b(8) * q(32);  q = ocquad(16) * xhalf(2)
  int b = blk >> 5, q = blk & 31;
  int oc0 = (q >> 1) * 4, xh = q & 1;
  __shared__ float Ws[4*288];
  int t = threadIdx.x;             // 512
  for (int idx = t; idx < 4*288; idx += 512) Ws[idx] = W[oc0*288 + idx];
  __syncthreads();
  int x = xh*16 + (t >> 5), y = t & 31;
  float a0 = bias[oc0+0], a1 = bias[oc0+1], a2 = bias[oc0+2], a3 = bias[oc0+3];
  const float* hb = h1 + b*32*1024;
  for (int ic = 0; ic < 32; ++ic) {
    const float* hc = hb + ic*1024;
    const float* w0 = Ws + 0*288 + ic*9;
    const float* w1 = Ws + 1*288 + ic*9;
    const float* w2 = Ws + 2*288 + ic*9;
    const float* w3 = Ws + 3*288 + ic*9;
#pragma unroll
    for (int dx = -1; dx <= 1; ++dx) {
      int xx = x + dx;
      bool okx = ((unsigned)xx < 32u);
#pragma unroll
      for (int dy = -1; dy <= 1; ++dy) {
        int yy = y + dy;
        float v = (okx && ((unsigned)yy < 32u)) ? hc[xx*32 + yy] : 0.f;
        int k = (dx+1)*3 + (dy+1);
        a0 = fmaf(v, w0[k], a0);
        a1 = fmaf(v, w1[k], a1);
        a2 = fmaf(v, w2[k], a2);
        a3 = fmaf(v, w3[k], a3);
      }
    }
  }
  int p = x*32 + y;
  h2[(b*64 + oc0+0)*1024 + p] = fmaxf(a0, 0.f);
  h2[(b*64 + oc0+1)*1024 + p] = fmaxf(a1, 0.f);
  h2[(b*64 + oc0+2)*1024 + p] = fmaxf(a2, 0.f);
  h2[(b*64 + oc0+3)*1024 + p] = fmaxf(a3, 0.f);
}

// ---------------- reduce: ft_max[b,c] = (sum_g Wg[c,g]) * sum_{x,y} h2*wq[y] ----------------
__global__ void k_reduce(const float* __restrict__ h2, const float* __restrict__ Wg,
                         const float* __restrict__ wq, float* __restrict__ ftmax) {
  int blk = blockIdx.x;            // 512 = b(8)*c(64)
  int b = blk >> 6, c = blk & 63;
  __shared__ float wqs[32];
  __shared__ float red[256];
  int t = threadIdx.x;             // 256
  if (t < 32) wqs[t] = wq[t];
  __syncthreads();
  const float* hb = h2 + (b*64 + c)*1024;
  float acc = 0.f;
  for (int i = t; i < 1024; i += 256) acc = fmaf(hb[i], wqs[i & 31], acc);
  red[t] = acc;
  __syncthreads();
  for (int s2 = 128; s2 > 0; s2 >>= 1) {
    if (t < s2) red[t] += red[t + s2];
    __syncthreads();
  }
  if (t == 0) {
    float sg = 0.f;
    for (int g = 0; g < 32; ++g) sg += Wg[c*32 + g];
    ftmax[b*64 + c] = sg * red[0];
  }
}

// ---------------- head (MFMA, split-f16): ----------------
// GEMM1: C1[(g,d), y] = V[(g,d),c] . h2[c,y]   (M=2048, N=32, K=64)
// h3 = relu(C1 + K[d]) -> split f16 -> LDS (y-swizzled d for bank spread)
// GEMM2: out[e, (y,g)] = W2[e,d] . h3[d,(y,g)] (M=32, N=1024, K=64), per g-half
__global__ __launch_bounds__(512) void k_head(
    const float* __restrict__ h2, const float* __restrict__ ftmax,
    const float* __restrict__ Wc31, const float* __restrict__ bc31,
    const float* __restrict__ bc32,
    const half8* __restrict__ VswH, const half8* __restrict__ VswL,
    const half8* __restrict__ W2swH, const half8* __restrict__ W2swL,
    float* __restrict__ out, float* __restrict__ blockmax) {
  __shared__ __align__(16) _Float16 h3H[512*72];   // [rowc=y*16+gl][d' swizzled], 72 KiB... (73728 B)
  __shared__ __align__(16) _Float16 h3L[512*72];
  __shared__ __align__(16) _Float16 h2H[32*72];    // [y][c]
  __shared__ __align__(16) _Float16 h2L[32*72];
  __shared__ float Ks[64];
  __shared__ float vbuf2[8*16];
  int blk = blockIdx.x;            // 256 = b(8)*x(32)
  int b = blk >> 5, x = blk & 31;
  int t = threadIdx.x;             // 512 = 8 waves
  int lane = t & 63, w = t >> 6;
  int n16 = lane & 15, quad = lane >> 4;

  // stage h2 as split-f16 [y][c]
  for (int idx = t; idx < 2048; idx += 512) {
    int c = idx & 63, y = idx >> 6;
    float v = h2[(b*64 + c)*1024 + x*32 + y];
    _Float16 hi = (_Float16)v;
    h2H[y*72 + c] = hi;
    h2L[y*72 + c] = (_Float16)(v - (float)hi);
  }
  if (t < 64) {
    float acc = bc31[t];
    for (int c = 0; c < 64; ++c)
      acc = fmaf(Wc31[t*128 + 64 + c], ftmax[b*64 + c], acc);
    Ks[t] = acc;
  }
  __syncthreads();

  // resident B-frags of GEMM1 (h2): B[k=c][n=y]
  half8 bh00, bh01, bh10, bh11, bl00, bl01, bl10, bl11;
  {
    int a00 = (0*16 + n16)*72 + 0*32 + quad*8;
    int a01 = (0*16 + n16)*72 + 1*32 + quad*8;
    int a10 = (1*16 + n16)*72 + 0*32 + quad*8;
    int a11 = (1*16 + n16)*72 + 1*32 + quad*8;
    bh00 = *(const half8*)&h2H[a00];  bl00 = *(const half8*)&h2L[a00];
    bh01 = *(const half8*)&h2H[a01];  bl01 = *(const half8*)&h2L[a01];
    bh10 = *(const half8*)&h2H[a10];  bl10 = *(const half8*)&h2L[a10];
    bh11 = *(const half8*)&h2H[a11];  bl11 = *(const half8*)&h2L[a11];
  }
  // resident A-frags of GEMM2 (W2): this wave's e-tile mt2 = w&1
  int mt2 = w & 1;
  half8 a2h0 = W2swH[(mt2*2 + 0)*64 + lane];
  half8 a2h1 = W2swH[(mt2*2 + 1)*64 + lane];
  half8 a2l0 = W2swL[(mt2*2 + 0)*64 + lane];
  half8 a2l1 = W2swL[(mt2*2 + 1)*64 + lane];
  float bias_e[4];
#pragma unroll
  for (int r = 0; r < 4; ++r) bias_e[r] = bc32[mt2*16 + quad*4 + r];

  float vmax[4] = {-3.4e38f, -3.4e38f, -3.4e38f, -3.4e38f};

  for (int h = 0; h < 2; ++h) {
    if (h) __syncthreads();          // protect h3 LDS reuse across halves
    // ---- GEMM1: this wave owns mt = h*64 + w*8 + i  (g = mt>>2) ----
    for (int i = 0; i < 8; ++i) {
      int mt = h*64 + w*8 + i;
      half8 ah0 = VswH[(mt*2 + 0)*64 + lane];
      half8 ah1 = VswH[(mt*2 + 1)*64 + lane];
      half8 al0 = VswL[(mt*2 + 0)*64 + lane];
      half8 al1 = VswL[(mt*2 + 1)*64 + lane];
      floatx4 acc0 = {0.f, 0.f, 0.f, 0.f};
      floatx4 acc1 = {0.f, 0.f, 0.f, 0.f};
      acc0 = MFMA16(ah0, bh00, acc0);  acc1 = MFMA16(ah0, bh10, acc1);
      acc0 = MFMA16(ah0, bl00, acc0);  acc1 = MFMA16(ah0, bl10, acc1);
      acc0 = MFMA16(al0, bh00, acc0);  acc1 = MFMA16(al0, bh10, acc1);
      acc0 = MFMA16(ah1, bh01, acc0);  acc1 = MFMA16(ah1, bh11, acc1);
      acc0 = MFMA16(ah1, bl01, acc0);  acc1 = MFMA16(ah1, bl11, acc1);
      acc0 = MFMA16(al1, bh01, acc0);  acc1 = MFMA16(al1, bh11, acc1);
      // post: +K[d], relu, split, LDS
      int g = mt >> 2, gl = g & 15;
      int dbase = (mt & 3)*16 + quad*4;          // true d of reg r: dbase + r
      float4 kv = *(const float4*)&Ks[dbase];
#pragma unroll
      for (int nt = 0; nt < 2; ++nt) {
        floatx4 a = nt ? acc1 : acc0;
        int y = nt*16 + n16;
        int rowc = y*16 + gl;
        int dsw = (dbase + y*8) & 63;            // y-swizzled d (runs stay contiguous)
        float v0 = fmaxf(a[0] + kv.x, 0.f);
        float v1 = fmaxf(a[1] + kv.y, 0.f);
        float v2 = fmaxf(a[2] + kv.z, 0.f);
        float v3 = fmaxf(a[3] + kv.w, 0.f);
        _Float16 c0 = (_Float16)v0, c1 = (_Float16)v1, c2 = (_Float16)v2, c3 = (_Float16)v3;
        half2v hh0 = {c0, c1}, hh1 = {c2, c3};
        half2v ll0 = {(_Float16)(v0 - (float)c0), (_Float16)(v1 - (float)c1)};
        half2v ll1 = {(_Float16)(v2 - (float)c2), (_Float16)(v3 - (float)c3)};
        int base = rowc*72 + dsw;
        *(half2v*)&h3H[base]     = hh0;
        *(half2v*)&h3H[base + 2] = hh1;
        *(half2v*)&h3L[base]     = ll0;
        *(half2v*)&h3L[base + 2] = ll1;
      }
    }
    __syncthreads();
    // ---- GEMM2: this wave owns nt2 = (w>>1)*8 + i  (y = nt2), e-tile mt2 ----
    for (int i = 0; i < 8; ++i) {
      int nt2 = (w >> 1)*8 + i;                  // = y
      int rowc = nt2*16 + n16;                   // gl = n16
      floatx4 acc = {0.f, 0.f, 0.f, 0.f};
      {
        int dsw0 = (0*32 + quad*8 + nt2*8) & 63;
        int dsw1 = (1*32 + quad*8 + nt2*8) & 63;
        half8 b2h0 = *(const half8*)&h3H[rowc*72 + dsw0];
        half8 b2l0 = *(const half8*)&h3L[rowc*72 + dsw0];
        half8 b2h1 = *(const half8*)&h3H[rowc*72 + dsw1];
        half8 b2l1 = *(const half8*)&h3L[rowc*72 + dsw1];
        acc = MFMA16(a2h0, b2h0, acc);
        acc = MFMA16(a2h0, b2l0, acc);
        acc = MFMA16(a2l0, b2h0, acc);
        acc = MFMA16(a2h1, b2h1, acc);
        acc = MFMA16(a2h1, b2l1, acc);
        acc = MFMA16(a2l1, b2h1, acc);
      }
      int y = nt2, g = h*16 + n16;
      size_t base = (((size_t)(b*32 + mt2*16 + quad*4))*1024 + (size_t)(x*32 + y))*32 + g;
#pragma unroll
      for (int r = 0; r < 4; ++r) {
        float v = acc[r] + bias_e[r];
        out[base + (size_t)r*32768] = v;
        vmax[r] = fmaxf(vmax[r], v);
      }
    }
  }
  // ft_g path: reduce vmax over the 16 col-lanes, then across waves
#pragma unroll
  for (int m = 1; m < 16; m <<= 1) {
#pragma unroll
    for (int r = 0; r < 4; ++r)
      vmax[r] = fmaxf(vmax[r], __shfl_xor(vmax[r], m, 64));
  }
  if (n16 == 0) {
#pragma unroll
    for (int r = 0; r < 4; ++r) vbuf2[w*16 + quad*4 + r] = vmax[r];
  }
  __syncthreads();
  if (t < 32) {
    int e = t, m2 = e >> 4, el = e & 15;
    float mm = fmaxf(fmaxf(vbuf2[(m2+0)*16 + el], vbuf2[(m2+2)*16 + el]),
                     fmaxf(vbuf2[(m2+4)*16 + el], vbuf2[(m2+6)*16 + el]));
    blockmax[blk*32 + e] = mm;
  }
}

// ---------------- finalize: ft_g[b,e] = max over x of blockmax ----------------
__global__ void k_final(const float* __restrict__ blockmax, float* __restrict__ ftg) {
  int t = threadIdx.x;             // 256 = b(8)*e(32)
  int b = t >> 5, e = t & 31;
  float m = -3.4e38f;
  for (int x = 0; x < 32; ++x) m = fmaxf(m, blockmax[(b*32 + x)*32 + e]);
  ftg[b*32 + e] = m;
}

extern "C" void kernel_launch(void* const* d_in, const int* in_sizes, int n_in,
                              void* d_out, int out_size, void* d_ws, size_t ws_size,
                              hipStream_t stream) {
  const float* inputs = (const float*)d_in[0];
  const float* scale  = (const float*)d_in[1];
  const float* sigma  = (const float*)d_in[2];
  const float* A      = (const float*)d_in[3];
  const float* icmp   = (const float*)d_in[4];
  // d_in[5]=res_pt(32), d_in[6]=res_r(8) — compile-time constants here
  const float* W1   = (const float*)d_in[7];
  const float* b1   = (const float*)d_in[8];
  const float* W2   = (const float*)d_in[9];
  const float* b2   = (const float*)d_in[10];
  const float* Wg   = (const float*)d_in[11];
  const float* Wc31 = (const float*)d_in[12];
  const float* bc31 = (const float*)d_in[13];
  const float* Wc32 = (const float*)d_in[14];
  const float* bc32 = (const float*)d_in[15];

  float* ws    = (float*)d_ws;
  float* ft    = ws;               // 65536
  float* h1    = ws + 65536;       // 262144
  float* h2    = ws + 327680;      // 524288
  float* ftmax = ws + 851968;      // 512
  float* bmax  = ws + 852480;      // 8192
  float* wq    = ws + 860672;      // 32
  _Float16* VswH  = (_Float16*)(ws + 860704);   // 131072 f16
  _Float16* VswL  = (_Float16*)(ws + 926240);   // 131072 f16
  _Float16* W2swH = (_Float16*)(ws + 991776);   // 2048 f16
  _Float16* W2swL = (_Float16*)(ws + 992800);   // 2048 f16
  float* out   = (float*)d_out;    // 8388608
  float* ftg   = out + 8388608;    // 256

  hipMemsetAsync(ft, 0, 65536*sizeof(float), stream);
  k_wq<<<1, 32, 0, stream>>>(wq);
  k_prepV<<<512, 256, 0, stream>>>(Wg, Wc31, VswH, VswL);
  k_prepW2<<<8, 256, 0, stream>>>(Wc32, W2swH, W2swL);
  k_scatter<<<1024, 256, 0, stream>>>(inputs, scale, sigma, A, icmp, ft);
  k_conv1<<<256, 1024, 0, stream>>>(ft, W1, b1, h1);
  k_conv2<<<256, 512, 0, stream>>>(h1, W2, b2, h2);
  k_reduce<<<512, 256, 0, stream>>>(h2, Wg, wq, ftmax);
  k_head<<<256, 512, 0, stream>>>(h2, ftmax, Wc31, bc31, bc32,
                                  (const half8*)VswH, (const half8*)VswL,
                                  (const half8*)W2swH, (const half8*)W2swL,
                                  out, bmax);
  k_final<<<1, 256, 0, stream>>>(bmax, ftg);
}